// Round 7
// baseline (105.951 us; speedup 1.0000x reference)
//
#include <hip/hip_runtime.h>

#define HW    36864
#define PX    144    // px per block: 36864 / 256 blocks
#define RST   136    // rel_s row stride (elements): 128 + 8 pad -> b128 reads 2-way only

typedef unsigned short u16;
typedef unsigned int   u32;
typedef __attribute__((ext_vector_type(8))) short bf16x8;
typedef __attribute__((ext_vector_type(4))) float f32x4;

__device__ __forceinline__ float bf2f(u32 u) {
    union { u32 i; float f; } c; c.i = u << 16; return c.f;
}
__device__ __forceinline__ u16 f2bf(float f) {
    union { float f; u32 i; } c; c.f = f;
    u32 r = (c.i + 0x7fffu + ((c.i >> 16) & 1u)) >> 16;  // RNE
    return (u16)r;
}
__device__ __forceinline__ u32 pack2(float a, float b) {
    return (u32)f2bf(a) | ((u32)f2bf(b) << 16);
}
__device__ __forceinline__ float sigf(float x) { return 1.0f / (1.0f + __expf(-x)); }

__device__ __forceinline__ void unpack8(uint4 v, float* o) {
    o[0] = bf2f(v.x & 0xffffu); o[1] = bf2f(v.x >> 16);
    o[2] = bf2f(v.y & 0xffffu); o[3] = bf2f(v.y >> 16);
    o[4] = bf2f(v.z & 0xffffu); o[5] = bf2f(v.z >> 16);
    o[6] = bf2f(v.w & 0xffffu); o[7] = bf2f(v.w >> 16);
}

template<int BF16>
__device__ __forceinline__ float ld1(const void* p, int idx) {
    return BF16 ? bf2f((u32)((const u16*)p)[idx]) : ((const float*)p)[idx];
}

// Block-wide dtype self-detect (identical criterion to the round-2 k_detect,
// which empirically selected the passing path). Includes a barrier; call
// before any LDS use, all threads. Returns true if THIS variant is wrong.
template<int BF16>
__device__ __forceinline__ bool wrong_dtype(const void* ml, int tid) {
    int pred = 0;
    if (tid < 128) {
        u16 v = ((const u16*)ml)[tid];
        u32 e = (v >> 7) & 0xffu;
        pred = ((v & 0x7fffu) == 0 || (e >= 90u && e <= 140u)) ? 1 : 0;
    }
    int cnt = __syncthreads_count(pred);
    return (cnt >= 100) != (BF16 != 0);
}

// ---------------------------------------------------------------------------
// k_rel: relN[n][m] = relu(ov(n,m) - ov(m,n)) as bf16, row-major (m contig).
// grid 128 (n), block 128 (m). Each thread computes BOTH directions using
// block-shared u_s = relu(WU[cn])*WP and v_s = relu(WV[cn])*WP.
// ---------------------------------------------------------------------------
template<int BF16>
__global__ __launch_bounds__(128) void k_rel(
    const void* __restrict__ ml,   const void* __restrict__ bbox,
    const void* __restrict__ WU,   const void* __restrict__ WV,
    const void* __restrict__ Wpos, const void* __restrict__ WP,
    const int* __restrict__ cls,   u16* __restrict__ relN)
{
    const int n = blockIdx.x, m = threadIdx.x;
    if (wrong_dtype<BF16>(ml, m)) return;

    __shared__ float u_s[128], v_s[128], wpos_s[256], wpp_s[64], bbn_s[4];

    const int cn = cls[n] - 1;
    {
        float wp = ld1<BF16>(WP, m);
        u_s[m] = fmaxf(ld1<BF16>(WU, cn * 128 + m), 0.f) * wp;
        v_s[m] = fmaxf(ld1<BF16>(WV, cn * 128 + m), 0.f) * wp;
    }
    wpos_s[m]       = ld1<BF16>(Wpos, m);
    wpos_s[128 + m] = ld1<BF16>(Wpos, 128 + m);
    if (m < 64) wpp_s[m] = ld1<BF16>(WP, 128 + m);
    if (m < 4)  bbn_s[m] = ld1<BF16>(bbox, n * 4 + m);
    __syncthreads();

    // class term, both directions
    const int cm = cls[m] - 1;
    float s1 = 0.f, s2 = 0.f;
    #pragma unroll 8
    for (int c = 0; c < 128; ++c) {
        float wv = ld1<BF16>(WV, cm * 128 + c);
        float wu = ld1<BF16>(WU, cm * 128 + c);
        s1 += u_s[c] * fmaxf(wv, 0.f);
        s2 += v_s[c] * fmaxf(wu, 0.f);
    }

    // position term, both directions
    const float xmn = bbn_s[0], ymn = bbn_s[1], xMn = bbn_s[2], yMn = bbn_s[3];
    const float wn = xMn - xmn, hn = yMn - ymn;
    const float xcn = 0.5f * (xmn + xMn), ycn = 0.5f * (ymn + yMn);
    const float xmm = ld1<BF16>(bbox, m * 4 + 0), ymm = ld1<BF16>(bbox, m * 4 + 1);
    const float xMm = ld1<BF16>(bbox, m * 4 + 2), yMm = ld1<BF16>(bbox, m * 4 + 3);
    const float wm = xMm - xmm, hm = yMm - ymm;
    const float xcm = 0.5f * (xmm + xMm), ycm = 0.5f * (ymm + yMm);

    const float p0 = -(xcn - xcm) / wn, p1 = -(ycn - ycm) / hn;
    const float p2 = __logf(wm / wn),   p3 = __logf(hm / hn);
    const float q0 = -(xcm - xcn) / wm, q1 = -(ycm - ycn) / hm;
    const float q2 = __logf(wn / wm),   q3 = __logf(hn / hm);

    #pragma unroll 8
    for (int d = 0; d < 64; ++d) {
        float w0 = wpos_s[d], w1 = wpos_s[64 + d], w2 = wpos_s[128 + d], w3 = wpos_s[192 + d];
        float wp = wpp_s[d];
        float t1 = p0 * w0 + p1 * w1 + p2 * w2 + p3 * w3;
        float t2 = q0 * w0 + q1 * w1 + q2 * w2 + q3 * w3;
        s1 += fmaxf(t1, 0.f) * wp;
        s2 += fmaxf(t2, 0.f) * wp;
    }

    float r = fmaxf(sigf(s1) - sigf(s2), 0.f);
    relN[n * 128 + m] = f2bf(r);
}

// ---------------------------------------------------------------------------
// k_main: out[n,px] = ml - ml*prob*(sum_m rel[n,m]*prob[m,px])  via MFMA.
// grid 256 x 256 threads (4 waves). Per block: n=128 full, px tile = 144.
// Wave w: n-tiles {32w, 32w+16}, 9 px-tiles of 16. K=128 in two LDS halves.
// rel_s: [n][RST] bf16 (A operand, k contiguous, b128). prob_s: [64][144]
// bf16 (B operand via 8x ds_read_u16, lanes consecutive px -> conflict-free).
// ---------------------------------------------------------------------------
template<int BF16>
__global__ __launch_bounds__(256) void k_main(
    const void* __restrict__ mlv, const u16* __restrict__ relN,
    void* __restrict__ outv)
{
    const int tid = threadIdx.x;
    if (wrong_dtype<BF16>(mlv, tid)) return;

    __shared__ u16 rel_s[128 * RST];   // 34816 B
    __shared__ u16 prob_s[64 * PX];    // 18432 B   (total 52 KB)

    const int px0 = blockIdx.x * PX;
    const int w    = tid >> 6;
    const int lane = tid & 63;
    const int col  = lane & 15;
    const int quad = lane >> 4;
    const int n0   = w * 32;

    // stage rel: re-stride 128x128 -> 128xRST (coalesced b128 both sides)
    for (int idx = tid; idx < 2048; idx += 256) {
        int r = idx >> 4, c = idx & 15;
        uint4 v = ((const uint4*)relN)[idx];
        *(uint4*)(rel_s + r * RST + c * 8) = v;
    }

    f32x4 acc[2][9];
    #pragma unroll
    for (int i = 0; i < 2; ++i)
        #pragma unroll
        for (int t = 0; t < 9; ++t) acc[i][t] = (f32x4){0.f, 0.f, 0.f, 0.f};

    for (int h = 0; h < 2; ++h) {
        __syncthreads();   // rel copy done (h=0) / previous-half readers done (h=1)
        // stage prob_s = sigmoid(ml[h*64 .. h*64+63][px0 .. px0+143]) as bf16
        for (int idx = tid; idx < 1152; idx += 256) {
            int r = idx / 18, c = idx - r * 18;
            size_t base = (size_t)(h * 64 + r) * HW + px0 + c * 8;
            float f[8];
            if (BF16) {
                uint4 v = *(const uint4*)((const u16*)mlv + base);
                unpack8(v, f);
            } else {
                float4 v0 = *(const float4*)((const float*)mlv + base);
                float4 v1 = *(const float4*)((const float*)mlv + base + 4);
                f[0] = v0.x; f[1] = v0.y; f[2] = v0.z; f[3] = v0.w;
                f[4] = v1.x; f[5] = v1.y; f[6] = v1.z; f[7] = v1.w;
            }
            uint4 o;
            o.x = pack2(sigf(f[0]), sigf(f[1]));
            o.y = pack2(sigf(f[2]), sigf(f[3]));
            o.z = pack2(sigf(f[4]), sigf(f[5]));
            o.w = pack2(sigf(f[6]), sigf(f[7]));
            *(uint4*)(prob_s + r * PX + c * 8) = o;
        }
        __syncthreads();

        #pragma unroll
        for (int ksl = 0; ksl < 2; ++ksl) {
            const int k0 = h * 64 + ksl * 32 + quad * 8;   // global k of this lane's 8
            bf16x8 a0 = *(const bf16x8*)(rel_s + (n0 + col) * RST + k0);
            bf16x8 a1 = *(const bf16x8*)(rel_s + (n0 + 16 + col) * RST + k0);
            const u16* bbase = prob_s + (ksl * 32 + quad * 8) * PX + col;
            #pragma unroll
            for (int t = 0; t < 9; ++t) {
                const u16* bp = bbase + t * 16;
                bf16x8 bfrag;
                #pragma unroll
                for (int j = 0; j < 8; ++j) bfrag[j] = (short)bp[j * PX];
                acc[0][t] = __builtin_amdgcn_mfma_f32_16x16x32_bf16(a0, bfrag, acc[0][t], 0, 0, 0);
                acc[1][t] = __builtin_amdgcn_mfma_f32_16x16x32_bf16(a1, bfrag, acc[1][t], 0, 0, 0);
            }
        }
    }

    // epilogue: C/D layout col=lane&15, row=quad*4+reg
    #pragma unroll
    for (int i = 0; i < 2; ++i) {
        #pragma unroll
        for (int t = 0; t < 9; ++t) {
            const int nb = n0 + i * 16 + quad * 4;
            const int px = px0 + t * 16 + col;
            #pragma unroll
            for (int r = 0; r < 4; ++r) {
                size_t off = (size_t)(nb + r) * HW + px;
                float mlvv = BF16 ? bf2f((u32)((const u16*)mlv)[off])
                                  : ((const float*)mlv)[off];
                float pr = sigf(mlvv);
                float o  = mlvv - mlvv * pr * acc[i][t][r];
                if (BF16) ((u16*)outv)[off] = f2bf(o);
                else      ((float*)outv)[off] = o;
            }
        }
    }
}

extern "C" void kernel_launch(void* const* d_in, const int* in_sizes, int n_in,
                              void* d_out, int out_size, void* d_ws, size_t ws_size,
                              hipStream_t stream) {
    const void* ml   = d_in[0];
    const void* bbox = d_in[1];
    const void* WU   = d_in[2];
    const void* WV   = d_in[3];
    const void* Wpos = d_in[4];
    const void* WP   = d_in[5];
    const int*  cls  = (const int*)d_in[6];

    u16* relN = (u16*)d_ws;   // 32 KB, [n][m] row-major bf16

    k_rel<1><<<dim3(128), dim3(128), 0, stream>>>(ml, bbox, WU, WV, Wpos, WP, cls, relN);
    k_rel<0><<<dim3(128), dim3(128), 0, stream>>>(ml, bbox, WU, WV, Wpos, WP, cls, relN);
    k_main<1><<<dim3(256), dim3(256), 0, stream>>>(ml, relN, d_out);
    k_main<0><<<dim3(256), dim3(256), 0, stream>>>(ml, relN, d_out);
}